// Round 13
// baseline (916.386 us; speedup 1.0000x reference)
//
#include <hip/hip_runtime.h>
#include <hip/hip_bf16.h>
#include <stdint.h>

#define BATCH 512
#define TSTEPS 64
#define DIN 1024
#define HID 512
#define G3 1536
#define MROWS (BATCH * TSTEPS)
#define POUT 512

typedef __attribute__((ext_vector_type(8))) short bf16x8;
typedef __attribute__((ext_vector_type(4))) float f32x4;

__device__ __forceinline__ float bf2f(short s) {
  union { unsigned u; float f; } v;
  v.u = ((unsigned)(unsigned short)s) << 16;
  return v.f;
}
__device__ __forceinline__ short f2bf(float f) {
  __hip_bfloat16 h = __float2bfloat16(f);
  short s;
  __builtin_memcpy(&s, &h, 2);
  return s;
}
__device__ __forceinline__ void gload_lds16(const void* g, void* l) {
  __builtin_amdgcn_global_load_lds(
      (const __attribute__((address_space(1))) void*)g,
      (__attribute__((address_space(3))) void*)l, 16, 0, 0);
}

// ---------------------------------------------------------------------------
// transpose + fp32->bf16 cast: out[c][r] = bf16(in[r][c])  (for W_in -> Wt)
// ---------------------------------------------------------------------------
__global__ __launch_bounds__(256) void transpose_cast(const float* __restrict__ in,
                                                      short* __restrict__ out,
                                                      int R, int C) {
  __shared__ float tile[32][33];
  const int c0 = blockIdx.x * 32, r0 = blockIdx.y * 32;
  const int tx = threadIdx.x & 31, ty = threadIdx.x >> 5;
#pragma unroll
  for (int i = 0; i < 4; ++i) {
    const int r = r0 + ty + i * 8;
    tile[ty + i * 8][tx] = in[(size_t)r * C + c0 + tx];
  }
  __syncthreads();
#pragma unroll
  for (int i = 0; i < 4; ++i) {
    const int c = c0 + ty + i * 8;
    out[(size_t)c * R + r0 + tx] = f2bf(tile[tx][ty + i * 8]);
  }
}

// ---------------------------------------------------------------------------
// Pack U (fp32 [512][1536]) -> Upk bf16 [16 cg][96 ur][64 slot][8 e];
// slot holds logical k-chunk (slot ^ (ur&7)) -- XOR swizzle pre-applied so
// the scan stages it LINEARLY with global_load_lds.
// ---------------------------------------------------------------------------
__global__ __launch_bounds__(256) void u_pack2(const float* __restrict__ U,
                                               short* __restrict__ Upk) {
  const unsigned idx = blockIdx.x * 256 + threadIdx.x;  // < 786432
  const unsigned cg = idx / 49152u;
  const unsigned rem = idx - cg * 49152u;
  const unsigned ur = rem >> 9;
  const unsigned r2 = rem & 511u;
  const unsigned s = r2 >> 3, e = r2 & 7u;
  const unsigned chunk = s ^ (ur & 7u);
  const unsigned k = chunk * 8u + e;
  const unsigned g = ur >> 5, cc = ur & 31u;
  const unsigned col = g * 512u + cg * 32u + cc;
  Upk[idx] = f2bf(U[(size_t)k * G3 + col]);
}

// ---------------------------------------------------------------------------
// Kernel 1: XG = bf16(X @ W_in + b_in), MFMA 128x128 BK=64.
// Output layout: XG[t][bg][cg][bl][g][cc] (64,16,16,32,3,32) -- each scan
// block's per-step 6KB slice is CONTIGUOUS. Per-XCD contiguous tile chunks.
// ---------------------------------------------------------------------------
__global__ __launch_bounds__(256) void gemm_xg_mfma(const float* __restrict__ X,
                                                    const short* __restrict__ Wt,
                                                    const float* __restrict__ bin,
                                                    __hip_bfloat16* __restrict__ XG) {
  __shared__ __align__(16) short As[128 * 64];
  __shared__ __align__(16) short Bs[128 * 64];
  const int tid = threadIdx.x;
  const int w = tid >> 6, l = tid & 63;
  const int lc = l & 15, lg = l >> 4;

  const int xcd = blockIdx.x & 7;
  const int idx = blockIdx.x >> 3;          // 0..383
  const int wg = xcd * 384 + idx;           // contiguous chunk per XCD
  const int rt = wg / 12, ct = wg % 12;     // 12 consecutive share row-panel
  const int row0 = rt * 128, col0 = ct * 128;

  const int wm = w >> 1, wn = w & 1;

  f32x4 acc[4][4];
#pragma unroll
  for (int mt = 0; mt < 4; ++mt)
#pragma unroll
    for (int nt = 0; nt < 4; ++nt) acc[mt][nt] = (f32x4){0.f, 0.f, 0.f, 0.f};

  const int tr = tid >> 3, p = tid & 7;

  for (int k0 = 0; k0 < DIN; k0 += 64) {
    float4 ar[4][2];
#pragma unroll
    for (int i = 0; i < 4; ++i) {
      const int r = i * 32 + tr;
      const int s = p ^ (r & 7);
      const float* xp = &X[(size_t)(row0 + r) * DIN + k0 + s * 8];
      ar[i][0] = *reinterpret_cast<const float4*>(xp);
      ar[i][1] = *reinterpret_cast<const float4*>(xp + 4);
    }
    __syncthreads();
#pragma unroll
    for (int i = 0; i < 4; ++i) {
      const int r = i * 32 + tr;
      bf16x8 v;
      v[0] = f2bf(ar[i][0].x); v[1] = f2bf(ar[i][0].y);
      v[2] = f2bf(ar[i][0].z); v[3] = f2bf(ar[i][0].w);
      v[4] = f2bf(ar[i][1].x); v[5] = f2bf(ar[i][1].y);
      v[6] = f2bf(ar[i][1].z); v[7] = f2bf(ar[i][1].w);
      *reinterpret_cast<bf16x8*>((char*)As + r * 128 + p * 16) = v;
    }
#pragma unroll
    for (int i = 0; i < 4; ++i) {
      const int rr = w * 32 + i * 8 + (l >> 3);
      const int pp = l & 7;
      const int s = pp ^ (rr & 7);
      gload_lds16(&Wt[(size_t)(col0 + rr) * DIN + k0 + s * 8],
                  (char*)Bs + (w * 32 + i * 8) * 128);
    }
    __syncthreads();
#pragma unroll
    for (int kc = 0; kc < 2; ++kc) {
      bf16x8 a[4], b[4];
#pragma unroll
      for (int mt = 0; mt < 4; ++mt) {
        const int R = wm * 64 + mt * 16 + lc;
        const int ch = (kc * 4 + lg) ^ (R & 7);
        a[mt] = *reinterpret_cast<const bf16x8*>((const char*)As + R * 128 + ch * 16);
      }
#pragma unroll
      for (int nt = 0; nt < 4; ++nt) {
        const int Rn = wn * 64 + nt * 16 + lc;
        const int ch = (kc * 4 + lg) ^ (Rn & 7);
        b[nt] = *reinterpret_cast<const bf16x8*>((const char*)Bs + Rn * 128 + ch * 16);
      }
#pragma unroll
      for (int mt = 0; mt < 4; ++mt)
#pragma unroll
        for (int nt = 0; nt < 4; ++nt)
          acc[mt][nt] = __builtin_amdgcn_mfma_f32_16x16x32_bf16(a[mt], b[nt],
                                                                acc[mt][nt], 0, 0, 0);
    }
  }

  float bv[4];
#pragma unroll
  for (int nt = 0; nt < 4; ++nt) bv[nt] = bin[col0 + wn * 64 + nt * 16 + lc];
#pragma unroll
  for (int mt = 0; mt < 4; ++mt) {
#pragma unroll
    for (int nt = 0; nt < 4; ++nt) {
      const int col = col0 + wn * 64 + nt * 16 + lc;
      const int g = col >> 9, cgc = (col >> 5) & 15, cc = col & 31;
#pragma unroll
      for (int rr = 0; rr < 4; ++rr) {
        const int m = row0 + wm * 64 + mt * 16 + lg * 4 + rr;
        const int t = m & 63, b = m >> 6;
        const size_t o =
            ((((size_t)t * 16 + (b >> 5)) * 16 + cgc) * 32 + (b & 31)) * 96 +
            g * 32 + cc;
        XG[o] = __float2bfloat16(acc[mt][nt][rr] + bv[nt]);
      }
    }
  }
}

// ---------------------------------------------------------------------------
// Kernel 2: persistent cooperative GRU scan.
// 256 blocks = 16 batch-groups x 16 col-groups. U-slice resident in LDS.
// Producer side unchanged (scattered u16 agent-atomic stores to the swizzled
// h_g image + drain barrier + agent-atomic flag). CONSUMER side new: after
// the poll succeeds, ONE agent-acquire fence (L1/L2 invalidate) per step,
// then PLAIN u64 loads of h_g -> L2-cacheable, so same-XCD consumers share
// one IF fetch. Correct because parity-(t&1) h_g is write-stable at the
// fabric during step t (writers target the other parity); the fence kills
// the only hazard (stale lines cached at step t-2).
// hS is ZERO-INITIALIZED (t=0 reads hold from hS; h(0)=0).
// ---------------------------------------------------------------------------
__global__ __launch_bounds__(256) void gru_scan_coop(
    const __hip_bfloat16* __restrict__ XG, const short* __restrict__ Upk,
    const float* __restrict__ brec, short* h_g, unsigned* bar,
    float* __restrict__ HT) {
  __shared__ __align__(16) short Us[96 * 512];   // 96 KB
  __shared__ __align__(16) short hS[32 * 512];   // 32 KB
  __shared__ __align__(16) short xgL[2][3072];   // 12 KB
  const int tid = threadIdx.x, w = tid >> 6, l = tid & 63;
  const int lc = l & 15, lg = l >> 4;
  const int bg = blockIdx.x >> 4, cgi = blockIdx.x & 15;
  const int b0 = bg * 32, c0 = cgi * 32;
  const int wm = w >> 1, wn = w & 1;
  unsigned* const flags = bar + bg * 16;

  // stage U slice once (pre-swizzled global, linear LDS dest)
  {
    const short* usrc = Upk + (size_t)cgi * 49152;
#pragma unroll
    for (int r = 0; r < 24; ++r)
      gload_lds16(usrc + (r * 256 + tid) * 8, Us + (r * 256 + (tid & ~63)) * 8);
  }
  // zero hS: t=0 computes with h=0 (gates read hold from hS at t=0)
  for (int i = tid; i < 4096; i += 256) ((unsigned long long*)hS)[i] = 0ull;

  const short* XGs = (const short*)XG;
  {  // stage xg(t=0): 6KB slice = 384 chunks (256 + 128), linear
    const short* xs = XGs + (size_t)bg * 49152 + (size_t)cgi * 3072;
    gload_lds16(xs + tid * 8, (char*)xgL[0] + w * 1024);
    if (tid < 128)
      gload_lds16(xs + (256 + tid) * 8, (char*)xgL[0] + 4096 + w * 1024);
  }

  const int j = c0 + wn * 16 + lc;  // this lane's h/gate column
  const float brz = brec[j], brr = brec[512 + j], brh = brec[1024 + j];
  const int arow = wm * 16 + lc;
  const int ur0 = wn * 16 + lc;

  __syncthreads();  // Us + hS + xg(0) ready (compiler drains vmcnt)

  for (int t = 0; t < TSTEPS; ++t) {
    f32x4 za0 = (f32x4){0.f, 0.f, 0.f, 0.f}, za1 = za0, za2 = za0;
    if (t > 0) {
      // ---- wait for all 16 producers of h(t) ----
      for (;;) {
        const unsigned f = __hip_atomic_load(&flags[l & 15], __ATOMIC_RELAXED,
                                             __HIP_MEMORY_SCOPE_AGENT);
        if (__all((int)(f >= (unsigned)t))) break;
        __builtin_amdgcn_s_sleep(1);
      }
      // ONE acquire fence per step: invalidate L1/L2 so the (stable) h image
      // refetches fresh from the fabric; subsequent plain loads may L2-hit
      // when a same-XCD block already refilled this step.
      __builtin_amdgcn_fence(__ATOMIC_ACQUIRE, "agent");
      // ---- coalesced h loads (PLAIN, cacheable) ----
      const unsigned long long* hsrc = (const unsigned long long*)(
          h_g + ((size_t)(t & 1) * BATCH + b0) * 512);
      unsigned long long v[16];
#pragma unroll
      for (int r = 0; r < 16; ++r)
        v[r] = hsrc[r * 256 + tid];
#pragma unroll
      for (int r = 0; r < 16; ++r)
        ((unsigned long long*)hS)[r * 256 + tid] = v[r];
      __syncthreads();  // hS ready

      // ---- hg = h @ U : 48 MFMAs (swizzled LDS, conflict-free b128) ----
#pragma unroll
      for (int kc = 0; kc < 16; ++kc) {
        const int s = kc * 4 + lg;
        const bf16x8 a = *(const bf16x8*)((const char*)hS + arow * 1024 +
                                          ((s ^ (arow & 7)) << 4));
        const char* ub = (const char*)Us + ur0 * 1024 + ((s ^ (ur0 & 7)) << 4);
        const bf16x8 bz = *(const bf16x8*)(ub);
        const bf16x8 brg = *(const bf16x8*)(ub + 32 * 1024);
        const bf16x8 bh = *(const bf16x8*)(ub + 64 * 1024);
        za0 = __builtin_amdgcn_mfma_f32_16x16x32_bf16(a, bz, za0, 0, 0, 0);
        za1 = __builtin_amdgcn_mfma_f32_16x16x32_bf16(a, brg, za1, 0, 0, 0);
        za2 = __builtin_amdgcn_mfma_f32_16x16x32_bf16(a, bh, za2, 0, 0, 0);
      }
    }

    // ---- gates in-register; C/D: col=lane&15, row=(lane>>4)*4+reg ----
    const short* xb = xgL[t & 1];
#pragma unroll
    for (int r = 0; r < 4; ++r) {
      const int lb = wm * 16 + lg * 4 + r;
      const float xz = bf2f(xb[lb * 96 + wn * 16 + lc]);
      const float xr = bf2f(xb[lb * 96 + 32 + wn * 16 + lc]);
      const float xh = bf2f(xb[lb * 96 + 64 + wn * 16 + lc]);
      const float z = 1.f / (1.f + __expf(-(xz + za0[r] + brz)));
      const float rg = 1.f / (1.f + __expf(-(xr + za1[r] + brr)));
      const float hc = fmaxf(fmaf(rg, za2[r] + brh, xh), 0.f);
      const int hoff = lb * 1024 + (((j >> 3) ^ (lb & 7)) << 4) + (j & 7) * 2;
      const float hold = bf2f(*(const short*)((const char*)hS + hoff));
      const float hnew = fmaf(z, hold - hc, hc);
      if (t == TSTEPS - 1) {
        HT[(size_t)(b0 + lb) * HID + j] = hnew;
      } else {
        // agent-atomic store: must reach the fabric past this XCD's L2
        __hip_atomic_store(
            (unsigned short*)((char*)h_g +
                              ((size_t)((t + 1) & 1) * BATCH + b0) * 1024 + hoff),
            (unsigned short)f2bf(hnew), __ATOMIC_RELAXED,
            __HIP_MEMORY_SCOPE_AGENT);
      }
    }
    if (t == TSTEPS - 1) break;

    __syncthreads();  // all waves' h stores drained (vmcnt 0 before barrier)
    if (tid == 0)
      __hip_atomic_store(&flags[cgi], (unsigned)(t + 1), __ATOMIC_RELAXED,
                         __HIP_MEMORY_SCOPE_AGENT);
    {  // stage xg(t+1) while flags propagate: full 6KB slice (384 chunks)
      const short* xs = XGs + ((size_t)(t + 1) * 16 + (size_t)bg) * 49152 +
                        (size_t)cgi * 3072;
      char* xd = (char*)xgL[(t + 1) & 1];
      gload_lds16(xs + tid * 8, xd + w * 1024);
      if (tid < 128)
        gload_lds16(xs + (256 + tid) * 8, xd + 4096 + w * 1024);
    }
  }
}

// ---------------------------------------------------------------------------
// Kernel 3: out = cat(hT,hT) @ W2 + b2 == hT @ (W2_top + W2_bot) + b2
// ---------------------------------------------------------------------------
__global__ __launch_bounds__(256) void final_proj(const float* __restrict__ HT,
                                                  const float* __restrict__ W2,
                                                  const float* __restrict__ b2,
                                                  float* __restrict__ OUT) {
  const int b = blockIdx.x >> 1;
  const int pp = ((blockIdx.x & 1) << 8) + threadIdx.x;
  float acc = b2[pp];
  const float* h = &HT[(size_t)b * HID];
  for (int k = 0; k < HID; ++k)
    acc = fmaf(h[k], W2[(size_t)k * POUT + pp] + W2[(size_t)(k + HID) * POUT + pp], acc);
  OUT[(size_t)b * POUT + pp] = acc;
}

// ---------------------------------------------------------------------------
extern "C" void kernel_launch(void* const* d_in, const int* in_sizes, int n_in,
                              void* d_out, int out_size, void* d_ws,
                              size_t ws_size, hipStream_t stream) {
  const float* X    = (const float*)d_in[0];
  const float* Win  = (const float*)d_in[1];
  const float* bin  = (const float*)d_in[2];
  const float* U    = (const float*)d_in[3];
  const float* brec = (const float*)d_in[4];
  const float* W2   = (const float*)d_in[5];
  const float* b2   = (const float*)d_in[6];
  float* OUT = (float*)d_out;

  char* ws = (char*)d_ws;
  size_t off = 0;
  __hip_bfloat16* XG = (__hip_bfloat16*)(ws + off); off += (size_t)MROWS * G3 * 2;  // 100.66 MB
  short* Wt   = (short*)(ws + off); off += (size_t)G3 * DIN * 2;                    // 3.15 MB
  short* Upk  = (short*)(ws + off); off += (size_t)G3 * HID * 2;                    // 1.57 MB
  float* HT   = (float*)(ws + off); off += (size_t)BATCH * HID * 4;                 // 1.05 MB
  short* h_g  = (short*)(ws + off); off += (size_t)2 * BATCH * HID * 2;             // 1.05 MB (dbuf)
  unsigned* bar = (unsigned*)(ws + off);                                            // 1 KB

  hipMemsetAsync(bar, 0, 1024, stream);  // flag slots; h_g needs no reset (each
                                         // parity buffer fully written before
                                         // first read every call)

  transpose_cast<<<dim3(G3 / 32, DIN / 32), 256, 0, stream>>>(Win, Wt, DIN, G3);
  u_pack2<<<(HID * G3) / 256, 256, 0, stream>>>(U, Upk);
  gemm_xg_mfma<<<(MROWS / 128) * (G3 / 128), 256, 0, stream>>>(X, Wt, bin, XG);

  const __hip_bfloat16* XGc = XG;
  const short* Upkc = Upk;
  void* args[] = {(void*)&XGc, (void*)&Upkc, (void*)&brec,
                  (void*)&h_g, (void*)&bar, (void*)&HT};
  hipLaunchCooperativeKernel((const void*)gru_scan_coop, dim3(256), dim3(256),
                             args, 0, stream);

  final_proj<<<(BATCH * POUT) / 256, 256, 0, stream>>>(HT, W2, b2, OUT);
}

// Round 14
// 575.556 us; speedup vs baseline: 1.5922x; 1.5922x over previous
//
#include <hip/hip_runtime.h>
#include <hip/hip_bf16.h>
#include <stdint.h>

#define BATCH 512
#define TSTEPS 64
#define DIN 1024
#define HID 512
#define G3 1536
#define MROWS (BATCH * TSTEPS)
#define POUT 512

typedef __attribute__((ext_vector_type(8))) short bf16x8;
typedef __attribute__((ext_vector_type(4))) float f32x4;

__device__ __forceinline__ float bf2f(short s) {
  union { unsigned u; float f; } v;
  v.u = ((unsigned)(unsigned short)s) << 16;
  return v.f;
}
__device__ __forceinline__ short f2bf(float f) {
  __hip_bfloat16 h = __float2bfloat16(f);
  short s;
  __builtin_memcpy(&s, &h, 2);
  return s;
}
__device__ __forceinline__ void gload_lds16(const void* g, void* l) {
  __builtin_amdgcn_global_load_lds(
      (const __attribute__((address_space(1))) void*)g,
      (__attribute__((address_space(3))) void*)l, 16, 0, 0);
}

// ---------------------------------------------------------------------------
// transpose + fp32->bf16 cast: out[c][r] = bf16(in[r][c])  (for W_in -> Wt)
// ---------------------------------------------------------------------------
__global__ __launch_bounds__(256) void transpose_cast(const float* __restrict__ in,
                                                      short* __restrict__ out,
                                                      int R, int C) {
  __shared__ float tile[32][33];
  const int c0 = blockIdx.x * 32, r0 = blockIdx.y * 32;
  const int tx = threadIdx.x & 31, ty = threadIdx.x >> 5;
#pragma unroll
  for (int i = 0; i < 4; ++i) {
    const int r = r0 + ty + i * 8;
    tile[ty + i * 8][tx] = in[(size_t)r * C + c0 + tx];
  }
  __syncthreads();
#pragma unroll
  for (int i = 0; i < 4; ++i) {
    const int c = c0 + ty + i * 8;
    out[(size_t)c * R + r0 + tx] = f2bf(tile[tx][ty + i * 8]);
  }
}

// ---------------------------------------------------------------------------
// Pack U (fp32 [512][1536]) -> Upk bf16 [16 cg][96 ur][64 slot][8 e];
// slot holds logical k-chunk (slot ^ (ur&7)) -- XOR swizzle pre-applied so
// the scan stages it LINEARLY with global_load_lds.
// ---------------------------------------------------------------------------
__global__ __launch_bounds__(256) void u_pack2(const float* __restrict__ U,
                                               short* __restrict__ Upk) {
  const unsigned idx = blockIdx.x * 256 + threadIdx.x;  // < 786432
  const unsigned cg = idx / 49152u;
  const unsigned rem = idx - cg * 49152u;
  const unsigned ur = rem >> 9;
  const unsigned r2 = rem & 511u;
  const unsigned s = r2 >> 3, e = r2 & 7u;
  const unsigned chunk = s ^ (ur & 7u);
  const unsigned k = chunk * 8u + e;
  const unsigned g = ur >> 5, cc = ur & 31u;
  const unsigned col = g * 512u + cg * 32u + cc;
  Upk[idx] = f2bf(U[(size_t)k * G3 + col]);
}

// ---------------------------------------------------------------------------
// Kernel 1: XG = bf16(X @ W_in + b_in), MFMA 128x128 BK=64.
// Output layout: XG[t][bg][cg][bl][g][cc] (64,16,16,32,3,32) -- each scan
// block's per-step 6KB slice is CONTIGUOUS. Per-XCD contiguous tile chunks.
// ---------------------------------------------------------------------------
__global__ __launch_bounds__(256) void gemm_xg_mfma(const float* __restrict__ X,
                                                    const short* __restrict__ Wt,
                                                    const float* __restrict__ bin,
                                                    __hip_bfloat16* __restrict__ XG) {
  __shared__ __align__(16) short As[128 * 64];
  __shared__ __align__(16) short Bs[128 * 64];
  const int tid = threadIdx.x;
  const int w = tid >> 6, l = tid & 63;
  const int lc = l & 15, lg = l >> 4;

  const int xcd = blockIdx.x & 7;
  const int idx = blockIdx.x >> 3;          // 0..383
  const int wg = xcd * 384 + idx;           // contiguous chunk per XCD
  const int rt = wg / 12, ct = wg % 12;     // 12 consecutive share row-panel
  const int row0 = rt * 128, col0 = ct * 128;

  const int wm = w >> 1, wn = w & 1;

  f32x4 acc[4][4];
#pragma unroll
  for (int mt = 0; mt < 4; ++mt)
#pragma unroll
    for (int nt = 0; nt < 4; ++nt) acc[mt][nt] = (f32x4){0.f, 0.f, 0.f, 0.f};

  const int tr = tid >> 3, p = tid & 7;

  for (int k0 = 0; k0 < DIN; k0 += 64) {
    float4 ar[4][2];
#pragma unroll
    for (int i = 0; i < 4; ++i) {
      const int r = i * 32 + tr;
      const int s = p ^ (r & 7);
      const float* xp = &X[(size_t)(row0 + r) * DIN + k0 + s * 8];
      ar[i][0] = *reinterpret_cast<const float4*>(xp);
      ar[i][1] = *reinterpret_cast<const float4*>(xp + 4);
    }
    __syncthreads();
#pragma unroll
    for (int i = 0; i < 4; ++i) {
      const int r = i * 32 + tr;
      bf16x8 v;
      v[0] = f2bf(ar[i][0].x); v[1] = f2bf(ar[i][0].y);
      v[2] = f2bf(ar[i][0].z); v[3] = f2bf(ar[i][0].w);
      v[4] = f2bf(ar[i][1].x); v[5] = f2bf(ar[i][1].y);
      v[6] = f2bf(ar[i][1].z); v[7] = f2bf(ar[i][1].w);
      *reinterpret_cast<bf16x8*>((char*)As + r * 128 + p * 16) = v;
    }
#pragma unroll
    for (int i = 0; i < 4; ++i) {
      const int rr = w * 32 + i * 8 + (l >> 3);
      const int pp = l & 7;
      const int s = pp ^ (rr & 7);
      gload_lds16(&Wt[(size_t)(col0 + rr) * DIN + k0 + s * 8],
                  (char*)Bs + (w * 32 + i * 8) * 128);
    }
    __syncthreads();
#pragma unroll
    for (int kc = 0; kc < 2; ++kc) {
      bf16x8 a[4], b[4];
#pragma unroll
      for (int mt = 0; mt < 4; ++mt) {
        const int R = wm * 64 + mt * 16 + lc;
        const int ch = (kc * 4 + lg) ^ (R & 7);
        a[mt] = *reinterpret_cast<const bf16x8*>((const char*)As + R * 128 + ch * 16);
      }
#pragma unroll
      for (int nt = 0; nt < 4; ++nt) {
        const int Rn = wn * 64 + nt * 16 + lc;
        const int ch = (kc * 4 + lg) ^ (Rn & 7);
        b[nt] = *reinterpret_cast<const bf16x8*>((const char*)Bs + Rn * 128 + ch * 16);
      }
#pragma unroll
      for (int mt = 0; mt < 4; ++mt)
#pragma unroll
        for (int nt = 0; nt < 4; ++nt)
          acc[mt][nt] = __builtin_amdgcn_mfma_f32_16x16x32_bf16(a[mt], b[nt],
                                                                acc[mt][nt], 0, 0, 0);
    }
  }

  float bv[4];
#pragma unroll
  for (int nt = 0; nt < 4; ++nt) bv[nt] = bin[col0 + wn * 64 + nt * 16 + lc];
#pragma unroll
  for (int mt = 0; mt < 4; ++mt) {
#pragma unroll
    for (int nt = 0; nt < 4; ++nt) {
      const int col = col0 + wn * 64 + nt * 16 + lc;
      const int g = col >> 9, cgc = (col >> 5) & 15, cc = col & 31;
#pragma unroll
      for (int rr = 0; rr < 4; ++rr) {
        const int m = row0 + wm * 64 + mt * 16 + lg * 4 + rr;
        const int t = m & 63, b = m >> 6;
        const size_t o =
            ((((size_t)t * 16 + (b >> 5)) * 16 + cgc) * 32 + (b & 31)) * 96 +
            g * 32 + cc;
        XG[o] = __float2bfloat16(acc[mt][nt][rr] + bv[nt]);
      }
    }
  }
}

// ---------------------------------------------------------------------------
// Kernel 2: persistent cooperative GRU scan with TAG-EMBEDDED h exchange.
// 256 blocks = 16 batch-groups x 16 col-groups. U-slice resident in LDS.
// h_g32 is u32[parity][b][512]: packet = {tag=t+1 (hi16) | bf16 h (lo16)}.
// Producers fire 4 relaxed agent-atomic u32 stores per lane and move on --
// NO drain barrier, NO flag, NO separate flag round-trip. Consumers poll
// their own 64KB slice (coalesced u64 atomic loads, per-packet tag check,
// __all retry): readiness arrives with the data -> one IF round-trip.
// Race-free by double-buffer induction (a block writes h(t+2) to parity p
// only after observing all h(t+1) tags, which are stored only after that
// producer's h(t) loads returned). Stale tags across calls: memset h_g32.
// hS is ZERO-INITIALIZED (t=0 reads hold from hS; h(0)=0).
// ---------------------------------------------------------------------------
__global__ __launch_bounds__(256) void gru_scan_coop(
    const __hip_bfloat16* __restrict__ XG, const short* __restrict__ Upk,
    const float* __restrict__ brec, unsigned* h_g32, float* __restrict__ HT) {
  __shared__ __align__(16) short Us[96 * 512];   // 96 KB
  __shared__ __align__(16) short hS[32 * 512];   // 32 KB
  __shared__ __align__(16) short xgL[2][3072];   // 12 KB
  const int tid = threadIdx.x, w = tid >> 6, l = tid & 63;
  const int lc = l & 15, lg = l >> 4;
  const int bg = blockIdx.x >> 4, cgi = blockIdx.x & 15;
  const int b0 = bg * 32, c0 = cgi * 32;
  const int wm = w >> 1, wn = w & 1;

  // stage U slice once (pre-swizzled global, linear LDS dest)
  {
    const short* usrc = Upk + (size_t)cgi * 49152;
#pragma unroll
    for (int r = 0; r < 24; ++r)
      gload_lds16(usrc + (r * 256 + tid) * 8, Us + (r * 256 + (tid & ~63)) * 8);
  }
  // zero hS: t=0 computes with h=0 (gates read hold from hS at t=0)
  for (int i = tid; i < 4096; i += 256) ((unsigned long long*)hS)[i] = 0ull;

  const short* XGs = (const short*)XG;
  {  // stage xg(t=0): 6KB slice = 384 chunks (256 + 128), linear
    const short* xs = XGs + (size_t)bg * 49152 + (size_t)cgi * 3072;
    gload_lds16(xs + tid * 8, (char*)xgL[0] + w * 1024);
    if (tid < 128)
      gload_lds16(xs + (256 + tid) * 8, (char*)xgL[0] + 4096 + w * 1024);
  }

  const int j = c0 + wn * 16 + lc;  // this lane's h/gate column
  const float brz = brec[j], brr = brec[512 + j], brh = brec[1024 + j];
  const int arow = wm * 16 + lc;
  const int ur0 = wn * 16 + lc;

  __syncthreads();  // Us + hS + xg(0) ready (compiler drains vmcnt)

  for (int t = 0; t < TSTEPS; ++t) {
    f32x4 za0 = (f32x4){0.f, 0.f, 0.f, 0.f}, za1 = za0, za2 = za0;
    if (t > 0) {
      // ---- poll-load own slice: tag==t on every packet (one IF RT) ----
      const unsigned long long* hsrc = (const unsigned long long*)(
          h_g32 + ((size_t)(t & 1) * BATCH + b0) * 512);
      unsigned long long v[32];
      const unsigned tg = (unsigned)t;
      for (;;) {
        bool ok = true;
#pragma unroll
        for (int r = 0; r < 32; ++r)
          v[r] = __hip_atomic_load(hsrc + r * 256 + tid, __ATOMIC_RELAXED,
                                   __HIP_MEMORY_SCOPE_AGENT);
#pragma unroll
        for (int r = 0; r < 32; ++r) {
          const unsigned t0 = (unsigned)((v[r] >> 16) & 0xFFFFu);
          const unsigned t1 = (unsigned)(v[r] >> 48);
          ok = ok && (t0 == tg) && (t1 == tg);
        }
        if (__all((int)ok)) break;
        __builtin_amdgcn_s_sleep(1);
      }
      __syncthreads();  // all waves' gates(t-1) reads of hS done
      // ---- strip tags, write hS with XOR swizzle ----
#pragma unroll
      for (int r = 0; r < 32; ++r) {
        const int idxq = r * 256 + tid;
        const int b = idxq >> 8, cp = idxq & 255;  // row, u64 col-pair
        const unsigned packed = (unsigned)(v[r] & 0xFFFFu) |
                                ((unsigned)((v[r] >> 32) & 0xFFFFu) << 16);
        const int ch = (cp >> 2) ^ (b & 7);
        *(unsigned*)((char*)hS + b * 1024 + (ch << 4) + ((cp & 3) << 2)) =
            packed;
      }
      __syncthreads();  // hS(t) ready

      // ---- hg = h @ U : 48 MFMAs (swizzled LDS, conflict-free b128) ----
#pragma unroll
      for (int kc = 0; kc < 16; ++kc) {
        const int s = kc * 4 + lg;
        const bf16x8 a = *(const bf16x8*)((const char*)hS + arow * 1024 +
                                          ((s ^ (arow & 7)) << 4));
        const char* ub = (const char*)Us + ur0 * 1024 + ((s ^ (ur0 & 7)) << 4);
        const bf16x8 bz = *(const bf16x8*)(ub);
        const bf16x8 brg = *(const bf16x8*)(ub + 32 * 1024);
        const bf16x8 bh = *(const bf16x8*)(ub + 64 * 1024);
        za0 = __builtin_amdgcn_mfma_f32_16x16x32_bf16(a, bz, za0, 0, 0, 0);
        za1 = __builtin_amdgcn_mfma_f32_16x16x32_bf16(a, brg, za1, 0, 0, 0);
        za2 = __builtin_amdgcn_mfma_f32_16x16x32_bf16(a, bh, za2, 0, 0, 0);
      }
    }

    // ---- gates in-register; C/D: col=lane&15, row=(lane>>4)*4+reg ----
    const short* xb = xgL[t & 1];
#pragma unroll
    for (int r = 0; r < 4; ++r) {
      const int lb = wm * 16 + lg * 4 + r;
      const float xz = bf2f(xb[lb * 96 + wn * 16 + lc]);
      const float xr = bf2f(xb[lb * 96 + 32 + wn * 16 + lc]);
      const float xh = bf2f(xb[lb * 96 + 64 + wn * 16 + lc]);
      const float z = 1.f / (1.f + __expf(-(xz + za0[r] + brz)));
      const float rg = 1.f / (1.f + __expf(-(xr + za1[r] + brr)));
      const float hc = fmaxf(fmaf(rg, za2[r] + brh, xh), 0.f);
      const int hoff = lb * 1024 + (((j >> 3) ^ (lb & 7)) << 4) + (j & 7) * 2;
      const float hold = bf2f(*(const short*)((const char*)hS + hoff));
      const float hnew = fmaf(z, hold - hc, hc);
      if (t == TSTEPS - 1) {
        HT[(size_t)(b0 + lb) * HID + j] = hnew;
      } else {
        // tagged packet: {tag = t+1 | bf16 h}; posted, no drain needed
        const unsigned pv = (unsigned)(unsigned short)f2bf(hnew) |
                            ((unsigned)(t + 1) << 16);
        __hip_atomic_store(
            h_g32 + ((size_t)((t + 1) & 1) * BATCH + b0 + lb) * 512 + j, pv,
            __ATOMIC_RELAXED, __HIP_MEMORY_SCOPE_AGENT);
      }
    }
    if (t == TSTEPS - 1) break;

    {  // stage xg(t+1): full 6KB slice (384 chunks); overlaps next poll
      const short* xs = XGs + ((size_t)(t + 1) * 16 + (size_t)bg) * 49152 +
                        (size_t)cgi * 3072;
      char* xd = (char*)xgL[(t + 1) & 1];
      gload_lds16(xs + tid * 8, xd + w * 1024);
      if (tid < 128)
        gload_lds16(xs + (256 + tid) * 8, xd + 4096 + w * 1024);
    }
  }
}

// ---------------------------------------------------------------------------
// Kernel 3: out = cat(hT,hT) @ W2 + b2 == hT @ (W2_top + W2_bot) + b2
// ---------------------------------------------------------------------------
__global__ __launch_bounds__(256) void final_proj(const float* __restrict__ HT,
                                                  const float* __restrict__ W2,
                                                  const float* __restrict__ b2,
                                                  float* __restrict__ OUT) {
  const int b = blockIdx.x >> 1;
  const int pp = ((blockIdx.x & 1) << 8) + threadIdx.x;
  float acc = b2[pp];
  const float* h = &HT[(size_t)b * HID];
  for (int k = 0; k < HID; ++k)
    acc = fmaf(h[k], W2[(size_t)k * POUT + pp] + W2[(size_t)(k + HID) * POUT + pp], acc);
  OUT[(size_t)b * POUT + pp] = acc;
}

// ---------------------------------------------------------------------------
extern "C" void kernel_launch(void* const* d_in, const int* in_sizes, int n_in,
                              void* d_out, int out_size, void* d_ws,
                              size_t ws_size, hipStream_t stream) {
  const float* X    = (const float*)d_in[0];
  const float* Win  = (const float*)d_in[1];
  const float* bin  = (const float*)d_in[2];
  const float* U    = (const float*)d_in[3];
  const float* brec = (const float*)d_in[4];
  const float* W2   = (const float*)d_in[5];
  const float* b2   = (const float*)d_in[6];
  float* OUT = (float*)d_out;

  char* ws = (char*)d_ws;
  size_t off = 0;
  __hip_bfloat16* XG = (__hip_bfloat16*)(ws + off); off += (size_t)MROWS * G3 * 2;  // 100.66 MB
  short* Wt   = (short*)(ws + off); off += (size_t)G3 * DIN * 2;                    // 3.15 MB
  short* Upk  = (short*)(ws + off); off += (size_t)G3 * HID * 2;                    // 1.57 MB
  float* HT   = (float*)(ws + off); off += (size_t)BATCH * HID * 4;                 // 1.05 MB
  unsigned* h_g32 = (unsigned*)(ws + off); off += (size_t)2 * BATCH * HID * 4;      // 2.10 MB (dbuf, tagged)

  // clear stale tags from previous call (poll waits for tag==t exactly)
  hipMemsetAsync(h_g32, 0, (size_t)2 * BATCH * HID * 4, stream);

  transpose_cast<<<dim3(G3 / 32, DIN / 32), 256, 0, stream>>>(Win, Wt, DIN, G3);
  u_pack2<<<(HID * G3) / 256, 256, 0, stream>>>(U, Upk);
  gemm_xg_mfma<<<(MROWS / 128) * (G3 / 128), 256, 0, stream>>>(X, Wt, bin, XG);

  const __hip_bfloat16* XGc = XG;
  const short* Upkc = Upk;
  void* args[] = {(void*)&XGc, (void*)&Upkc, (void*)&brec,
                  (void*)&h_g32, (void*)&HT};
  hipLaunchCooperativeKernel((const void*)gru_scan_coop, dim3(256), dim3(256),
                             args, 0, stream);

  final_proj<<<(BATCH * POUT) / 256, 256, 0, stream>>>(HT, W2, b2, OUT);
}

// Round 15
// 470.570 us; speedup vs baseline: 1.9474x; 1.2231x over previous
//
#include <hip/hip_runtime.h>
#include <hip/hip_bf16.h>
#include <stdint.h>

#define BATCH 512
#define TSTEPS 64
#define DIN 1024
#define HID 512
#define G3 1536
#define MROWS (BATCH * TSTEPS)
#define POUT 512

typedef __attribute__((ext_vector_type(8))) short bf16x8;
typedef __attribute__((ext_vector_type(4))) float f32x4;

__device__ __forceinline__ float bf2f(short s) {
  union { unsigned u; float f; } v;
  v.u = ((unsigned)(unsigned short)s) << 16;
  return v.f;
}
__device__ __forceinline__ short f2bf(float f) {
  __hip_bfloat16 h = __float2bfloat16(f);
  short s;
  __builtin_memcpy(&s, &h, 2);
  return s;
}
__device__ __forceinline__ void gload_lds16(const void* g, void* l) {
  __builtin_amdgcn_global_load_lds(
      (const __attribute__((address_space(1))) void*)g,
      (__attribute__((address_space(3))) void*)l, 16, 0, 0);
}

// ---------------------------------------------------------------------------
// transpose + fp32->bf16 cast: out[c][r] = bf16(in[r][c])  (for W_in -> Wt)
// ---------------------------------------------------------------------------
__global__ __launch_bounds__(256) void transpose_cast(const float* __restrict__ in,
                                                      short* __restrict__ out,
                                                      int R, int C) {
  __shared__ float tile[32][33];
  const int c0 = blockIdx.x * 32, r0 = blockIdx.y * 32;
  const int tx = threadIdx.x & 31, ty = threadIdx.x >> 5;
#pragma unroll
  for (int i = 0; i < 4; ++i) {
    const int r = r0 + ty + i * 8;
    tile[ty + i * 8][tx] = in[(size_t)r * C + c0 + tx];
  }
  __syncthreads();
#pragma unroll
  for (int i = 0; i < 4; ++i) {
    const int c = c0 + ty + i * 8;
    out[(size_t)c * R + r0 + tx] = f2bf(tile[tx][ty + i * 8]);
  }
}

// ---------------------------------------------------------------------------
// Pack U (fp32 [512][1536]) -> Upk2 bf16 [cg8][f48][wn4][lg4][lc16][e8]:
// thread (wn,lg,lc) of col-group cg reads fragment f = g*16+kc as one
// contiguous 16B chunk (register-resident U in the scan).
// ---------------------------------------------------------------------------
__global__ __launch_bounds__(256) void u_pack2(const float* __restrict__ U,
                                               short* __restrict__ Upk2) {
  const unsigned idx = blockIdx.x * 256 + threadIdx.x;  // < 786432
  const unsigned e = idx & 7u;
  unsigned tmp = idx >> 3;
  const unsigned lc = tmp & 15u; tmp >>= 4;
  const unsigned lg = tmp & 3u;  tmp >>= 2;
  const unsigned wn = tmp & 3u;  tmp >>= 2;  // tmp = cg*48 + f
  const unsigned f = tmp % 48u;
  const unsigned cg = tmp / 48u;
  const unsigned g = f >> 4, kc = f & 15u;
  const unsigned k = kc * 32u + lg * 8u + e;
  const unsigned col = g * 512u + cg * 64u + wn * 16u + lc;
  Upk2[idx] = f2bf(U[(size_t)k * G3 + col]);
}

// ---------------------------------------------------------------------------
// Kernel 1: XG = bf16(X @ W_in + b_in), MFMA 128x128 BK=64.
// Output layout: XG[t][bg16][cg8][bl32][g3][cc64] -- each scan block's
// per-step 12KB slice is CONTIGUOUS. Per-XCD contiguous tile chunks.
// ---------------------------------------------------------------------------
__global__ __launch_bounds__(256) void gemm_xg_mfma(const float* __restrict__ X,
                                                    const short* __restrict__ Wt,
                                                    const float* __restrict__ bin,
                                                    __hip_bfloat16* __restrict__ XG) {
  __shared__ __align__(16) short As[128 * 64];
  __shared__ __align__(16) short Bs[128 * 64];
  const int tid = threadIdx.x;
  const int w = tid >> 6, l = tid & 63;
  const int lc = l & 15, lg = l >> 4;

  const int xcd = blockIdx.x & 7;
  const int idx = blockIdx.x >> 3;          // 0..383
  const int wg = xcd * 384 + idx;           // contiguous chunk per XCD
  const int rt = wg / 12, ct = wg % 12;     // 12 consecutive share row-panel
  const int row0 = rt * 128, col0 = ct * 128;

  const int wm = w >> 1, wn = w & 1;

  f32x4 acc[4][4];
#pragma unroll
  for (int mt = 0; mt < 4; ++mt)
#pragma unroll
    for (int nt = 0; nt < 4; ++nt) acc[mt][nt] = (f32x4){0.f, 0.f, 0.f, 0.f};

  const int tr = tid >> 3, p = tid & 7;

  for (int k0 = 0; k0 < DIN; k0 += 64) {
    float4 ar[4][2];
#pragma unroll
    for (int i = 0; i < 4; ++i) {
      const int r = i * 32 + tr;
      const int s = p ^ (r & 7);
      const float* xp = &X[(size_t)(row0 + r) * DIN + k0 + s * 8];
      ar[i][0] = *reinterpret_cast<const float4*>(xp);
      ar[i][1] = *reinterpret_cast<const float4*>(xp + 4);
    }
    __syncthreads();
#pragma unroll
    for (int i = 0; i < 4; ++i) {
      const int r = i * 32 + tr;
      bf16x8 v;
      v[0] = f2bf(ar[i][0].x); v[1] = f2bf(ar[i][0].y);
      v[2] = f2bf(ar[i][0].z); v[3] = f2bf(ar[i][0].w);
      v[4] = f2bf(ar[i][1].x); v[5] = f2bf(ar[i][1].y);
      v[6] = f2bf(ar[i][1].z); v[7] = f2bf(ar[i][1].w);
      *reinterpret_cast<bf16x8*>((char*)As + r * 128 + p * 16) = v;
    }
#pragma unroll
    for (int i = 0; i < 4; ++i) {
      const int rr = w * 32 + i * 8 + (l >> 3);
      const int pp = l & 7;
      const int s = pp ^ (rr & 7);
      gload_lds16(&Wt[(size_t)(col0 + rr) * DIN + k0 + s * 8],
                  (char*)Bs + (w * 32 + i * 8) * 128);
    }
    __syncthreads();
#pragma unroll
    for (int kc = 0; kc < 2; ++kc) {
      bf16x8 a[4], b[4];
#pragma unroll
      for (int mt = 0; mt < 4; ++mt) {
        const int R = wm * 64 + mt * 16 + lc;
        const int ch = (kc * 4 + lg) ^ (R & 7);
        a[mt] = *reinterpret_cast<const bf16x8*>((const char*)As + R * 128 + ch * 16);
      }
#pragma unroll
      for (int nt = 0; nt < 4; ++nt) {
        const int Rn = wn * 64 + nt * 16 + lc;
        const int ch = (kc * 4 + lg) ^ (Rn & 7);
        b[nt] = *reinterpret_cast<const bf16x8*>((const char*)Bs + Rn * 128 + ch * 16);
      }
#pragma unroll
      for (int mt = 0; mt < 4; ++mt)
#pragma unroll
        for (int nt = 0; nt < 4; ++nt)
          acc[mt][nt] = __builtin_amdgcn_mfma_f32_16x16x32_bf16(a[mt], b[nt],
                                                                acc[mt][nt], 0, 0, 0);
    }
  }

  float bv[4];
#pragma unroll
  for (int nt = 0; nt < 4; ++nt) bv[nt] = bin[col0 + wn * 64 + nt * 16 + lc];
#pragma unroll
  for (int mt = 0; mt < 4; ++mt) {
#pragma unroll
    for (int nt = 0; nt < 4; ++nt) {
      const int col = col0 + wn * 64 + nt * 16 + lc;
      const int g = col >> 9;
      const int rem = col & 511;
      const int cgc = rem >> 6, cc = rem & 63;
#pragma unroll
      for (int rr = 0; rr < 4; ++rr) {
        const int m = row0 + wm * 64 + mt * 16 + lg * 4 + rr;
        const int t = m & 63, b = m >> 6;
        const size_t o =
            ((((size_t)t * 16 + (b >> 5)) * 8 + cgc) * 32 + (b & 31)) * 192 +
            g * 64 + cc;
        XG[o] = __float2bfloat16(acc[mt][nt][rr] + bv[nt]);
      }
    }
  }
}

// ---------------------------------------------------------------------------
// Kernel 2: persistent cooperative GRU scan, U REGISTER-RESIDENT.
// 128 blocks (16 bg x 8 cg) x 512 threads (8 waves = 2 wm x 4 wn).
// Each block: 32 batches x 64 h-cols. Per thread: 48 U B-frags (192 VGPR)
// loaded once at t=0, held all 64 steps -> no U LDS, no B-side ds_reads.
// h exchange = R11 proven protocol verbatim (scattered u16 agent-atomic
// stores into swizzled h image, drain barrier, per-producer flags, __all
// poll, linear u64 atomic consumer loads, parity double-buffer); consumers
// per h byte halved (8 cg) -> h broadcast 4 MB/step.
// hS ZERO-INITIALIZED (t=0 reads hold from hS; h(0)=0).
// ---------------------------------------------------------------------------
__global__ __launch_bounds__(512, 2) void gru_scan_coop(
    const __hip_bfloat16* __restrict__ XG, const short* __restrict__ Upk2,
    const float* __restrict__ brec, short* h_g, unsigned* bar,
    float* __restrict__ HT) {
  __shared__ __align__(16) short hS[32 * 512];   // 32 KB (swizzled image)
  __shared__ __align__(16) short xgL[2][6144];   // 24 KB
  const int tid = threadIdx.x, w = tid >> 6, l = tid & 63;
  const int lc = l & 15, lg = l >> 4;
  const int bg = blockIdx.x >> 3, cgi = blockIdx.x & 7;
  const int b0 = bg * 32, c0 = cgi * 64;
  const int wm = w & 1, wn = w >> 1;  // 2 batch-tiles x 4 col-tiles
  unsigned* const flags = bar + bg * 16;

  // ---- U fragments -> VGPRs (48 x bf16x8, coalesced 16B loads) ----
  bf16x8 ub[3][16];
#pragma unroll
  for (int g = 0; g < 3; ++g)
#pragma unroll
    for (int kc = 0; kc < 16; ++kc)
      ub[g][kc] = *reinterpret_cast<const bf16x8*>(
          Upk2 + ((((size_t)cgi * 48 + g * 16 + kc) * 4 + wn) * 4 + lg) * 128 +
          lc * 8);

  // zero hS: t=0 computes with h=0 (gates read hold from hS at t=0)
  for (int i = tid; i < 4096; i += 512) ((unsigned long long*)hS)[i] = 0ull;

  const short* XGs = (const short*)XG;
  {  // stage xg(t=0): 12KB slice = 768 chunks (512 + 256), linear
    const short* xs = XGs + ((size_t)bg * 8 + cgi) * 6144;
    gload_lds16(xs + tid * 8, (char*)xgL[0] + w * 1024);
    if (tid < 256)
      gload_lds16(xs + (512 + tid) * 8, (char*)xgL[0] + 8192 + w * 1024);
  }

  const int j = c0 + wn * 16 + lc;  // this lane's h/gate column
  const float brz = brec[j], brr = brec[512 + j], brh = brec[1024 + j];
  const int arow = wm * 16 + lc;

  __syncthreads();  // hS + xg(0) ready (compiler drains vmcnt)

  for (int t = 0; t < TSTEPS; ++t) {
    f32x4 za0 = (f32x4){0.f, 0.f, 0.f, 0.f}, za1 = za0, za2 = za0;
    if (t > 0) {
      // ---- wait for all 8 producers of h(t) ----
      for (;;) {
        const unsigned f = __hip_atomic_load(&flags[l & 7], __ATOMIC_RELAXED,
                                             __HIP_MEMORY_SCOPE_AGENT);
        if (__all((int)(f >= (unsigned)t))) break;
        __builtin_amdgcn_s_sleep(1);
      }
      // ---- coalesced h loads (relaxed agent atomics, swizzled image) ----
      const unsigned long long* hsrc = (const unsigned long long*)(
          h_g + ((size_t)(t & 1) * BATCH + b0) * 512);
      unsigned long long v[8];
#pragma unroll
      for (int r = 0; r < 8; ++r)
        v[r] = __hip_atomic_load(hsrc + r * 512 + tid, __ATOMIC_RELAXED,
                                 __HIP_MEMORY_SCOPE_AGENT);
#pragma unroll
      for (int r = 0; r < 8; ++r)
        ((unsigned long long*)hS)[r * 512 + tid] = v[r];
      __syncthreads();  // hS ready

      // ---- hg = h @ U : 48 MFMAs, B from VGPRs, A from swizzled hS ----
#pragma unroll
      for (int kc = 0; kc < 16; ++kc) {
        const int s = kc * 4 + lg;
        const bf16x8 a = *(const bf16x8*)((const char*)hS + arow * 1024 +
                                          ((s ^ (arow & 7)) << 4));
        za0 = __builtin_amdgcn_mfma_f32_16x16x32_bf16(a, ub[0][kc], za0, 0, 0, 0);
        za1 = __builtin_amdgcn_mfma_f32_16x16x32_bf16(a, ub[1][kc], za1, 0, 0, 0);
        za2 = __builtin_amdgcn_mfma_f32_16x16x32_bf16(a, ub[2][kc], za2, 0, 0, 0);
      }
    }

    // ---- gates in-register; C/D: col=lane&15, row=(lane>>4)*4+reg ----
    const short* xb = xgL[t & 1];
#pragma unroll
    for (int r = 0; r < 4; ++r) {
      const int lb = wm * 16 + lg * 4 + r;
      const float xz = bf2f(xb[lb * 192 + wn * 16 + lc]);
      const float xr = bf2f(xb[lb * 192 + 64 + wn * 16 + lc]);
      const float xh = bf2f(xb[lb * 192 + 128 + wn * 16 + lc]);
      const float z = 1.f / (1.f + __expf(-(xz + za0[r] + brz)));
      const float rg = 1.f / (1.f + __expf(-(xr + za1[r] + brr)));
      const float hc = fmaxf(fmaf(rg, za2[r] + brh, xh), 0.f);
      const int hoff = lb * 1024 + (((j >> 3) ^ (lb & 7)) << 4) + (j & 7) * 2;
      const float hold = bf2f(*(const short*)((const char*)hS + hoff));
      const float hnew = fmaf(z, hold - hc, hc);
      if (t == TSTEPS - 1) {
        HT[(size_t)(b0 + lb) * HID + j] = hnew;
      } else {
        __hip_atomic_store(
            (unsigned short*)((char*)h_g +
                              ((size_t)((t + 1) & 1) * BATCH + b0) * 1024 + hoff),
            (unsigned short)f2bf(hnew), __ATOMIC_RELAXED,
            __HIP_MEMORY_SCOPE_AGENT);
      }
    }
    if (t == TSTEPS - 1) break;

    __syncthreads();  // all waves' h stores drained (vmcnt 0 before barrier)
    if (tid == 0)
      __hip_atomic_store(&flags[cgi], (unsigned)(t + 1), __ATOMIC_RELAXED,
                         __HIP_MEMORY_SCOPE_AGENT);
    {  // stage xg(t+1) while flags propagate: 12KB slice (768 chunks)
      const short* xs = XGs + (((size_t)(t + 1) * 16 + bg) * 8 + cgi) * 6144;
      char* xd = (char*)xgL[(t + 1) & 1];
      gload_lds16(xs + tid * 8, xd + w * 1024);
      if (tid < 256)
        gload_lds16(xs + (512 + tid) * 8, xd + 8192 + w * 1024);
    }
  }
}

// ---------------------------------------------------------------------------
// Kernel 3: out = cat(hT,hT) @ W2 + b2 == hT @ (W2_top + W2_bot) + b2
// ---------------------------------------------------------------------------
__global__ __launch_bounds__(256) void final_proj(const float* __restrict__ HT,
                                                  const float* __restrict__ W2,
                                                  const float* __restrict__ b2,
                                                  float* __restrict__ OUT) {
  const int b = blockIdx.x >> 1;
  const int pp = ((blockIdx.x & 1) << 8) + threadIdx.x;
  float acc = b2[pp];
  const float* h = &HT[(size_t)b * HID];
  for (int k = 0; k < HID; ++k)
    acc = fmaf(h[k], W2[(size_t)k * POUT + pp] + W2[(size_t)(k + HID) * POUT + pp], acc);
  OUT[(size_t)b * POUT + pp] = acc;
}

// ---------------------------------------------------------------------------
extern "C" void kernel_launch(void* const* d_in, const int* in_sizes, int n_in,
                              void* d_out, int out_size, void* d_ws,
                              size_t ws_size, hipStream_t stream) {
  const float* X    = (const float*)d_in[0];
  const float* Win  = (const float*)d_in[1];
  const float* bin  = (const float*)d_in[2];
  const float* U    = (const float*)d_in[3];
  const float* brec = (const float*)d_in[4];
  const float* W2   = (const float*)d_in[5];
  const float* b2   = (const float*)d_in[6];
  float* OUT = (float*)d_out;

  char* ws = (char*)d_ws;
  size_t off = 0;
  __hip_bfloat16* XG = (__hip_bfloat16*)(ws + off); off += (size_t)MROWS * G3 * 2;  // 100.66 MB
  short* Wt   = (short*)(ws + off); off += (size_t)G3 * DIN * 2;                    // 3.15 MB
  short* Upk2 = (short*)(ws + off); off += (size_t)G3 * HID * 2;                    // 1.57 MB
  float* HT   = (float*)(ws + off); off += (size_t)BATCH * HID * 4;                 // 1.05 MB
  short* h_g  = (short*)(ws + off); off += (size_t)2 * BATCH * HID * 2;             // 1.05 MB (dbuf)
  unsigned* bar = (unsigned*)(ws + off);                                            // 1 KB

  hipMemsetAsync(bar, 0, 1024, stream);  // flag slots; h_g needs no reset (each
                                         // parity buffer fully written before
                                         // first read every call)

  transpose_cast<<<dim3(G3 / 32, DIN / 32), 256, 0, stream>>>(Win, Wt, DIN, G3);
  u_pack2<<<(HID * G3) / 256, 256, 0, stream>>>(U, Upk2);
  gemm_xg_mfma<<<(MROWS / 128) * (G3 / 128), 256, 0, stream>>>(X, Wt, bin, XG);

  const __hip_bfloat16* XGc = XG;
  const short* Upkc = Upk2;
  void* args[] = {(void*)&XGc, (void*)&Upkc, (void*)&brec,
                  (void*)&h_g, (void*)&bar, (void*)&HT};
  hipLaunchCooperativeKernel((const void*)gru_scan_coop, dim3(128), dim3(512),
                             args, 0, stream);

  final_proj<<<(BATCH * POUT) / 256, 256, 0, stream>>>(HT, W2, b2, OUT);
}